// Round 8
// baseline (189.390 us; speedup 1.0000x reference)
//
#include <hip/hip_runtime.h>
#include <stdint.h>

#define D_ 128
#define H_ 8
#define B_ 4
#define L_ 2048
#define NH (B_*H_)

typedef __bf16 bf16x8 __attribute__((ext_vector_type(8)));
typedef float f32x4 __attribute__((ext_vector_type(4)));
typedef float f32x16 __attribute__((ext_vector_type(16)));
typedef unsigned short u16;
typedef u16 u16x2 __attribute__((ext_vector_type(2)));
typedef u16 u16x4 __attribute__((ext_vector_type(4)));
typedef u16 u16x8 __attribute__((ext_vector_type(8)));
typedef uint32_t u32x4 __attribute__((ext_vector_type(4)));
typedef float fvec4 __attribute__((ext_vector_type(4)));

__device__ __forceinline__ u16 f2b(float f){
    uint32_t u = __builtin_bit_cast(uint32_t, f);
    u += 0x7fffu + ((u >> 16) & 1u);
    return (u16)(u >> 16);
}
__device__ __forceinline__ u16 f2b_native(float f){
    return __builtin_bit_cast(u16, (__bf16)f);
}
// pack 2 f32 -> u32 of 2 bf16 (compiler emits v_cvt_pk_bf16_f32)
__device__ __forceinline__ uint32_t pk2(float a, float b){
    u16x2 v = { f2b_native(a), f2b_native(b) };
    return __builtin_bit_cast(uint32_t, v);
}
__device__ __forceinline__ bf16x8 asbf(u16x8 v){ return __builtin_bit_cast(bf16x8, v); }
#define MFMA(a,b,c)   __builtin_amdgcn_mfma_f32_16x16x32_bf16((a),(b),(c),0,0,0)
#define MFMA32(a,b,c) __builtin_amdgcn_mfma_f32_32x32x16_bf16((a),(b),(c),0,0,0)

// async global->LDS, 16B per lane; LDS dest is wave-uniform base + lane*16
__device__ __forceinline__ void gld16(const u16* g, u16* l){
    __builtin_amdgcn_global_load_lds(
        (const __attribute__((address_space(1))) void*)g,
        (__attribute__((address_space(3))) void*)l, 16, 0, 0);
}

// ---------------- kernel 0: convert x fp32 -> bf16 ----------------
__global__ __launch_bounds__(256)
void cvt_x(const float* __restrict__ x, u16* __restrict__ xb){
    size_t i = ((size_t)blockIdx.x*256 + threadIdx.x)*8;
    fvec4 lo = *(const fvec4*)&x[i];
    fvec4 hi = *(const fvec4*)&x[i+4];
    u16x8 u;
    for (int j=0;j<4;++j){ u[j]=f2b(lo[j]); u[4+j]=f2b(hi[j]); }
    *(u16x8*)&xb[i] = u;
}

// ---------------- kernel 1: QKV projection ----------------
// Q: q_ws[bh][l][d] (pre-scaled by log2e/sqrt(D)), K: k_ws[bh][l][d], V: v_ws[bh][d][l]
__global__ __launch_bounds__(256)
void qkv_proj(const u16* __restrict__ xb,
              const float* __restrict__ Wq, const float* __restrict__ Wk, const float* __restrict__ Wv,
              u16* __restrict__ q_ws, u16* __restrict__ k_ws, u16* __restrict__ v_ws)
{
    const int head = blockIdx.x;
    const int rt   = blockIdx.y;
    const int mat  = blockIdx.z;
    const float* W = (mat==0) ? Wq : ((mat==1) ? Wk : Wv);

    __shared__ __align__(16) u16 Ws[128][136];

    const int t = threadIdx.x;
    const int row0 = rt*128;

    for (int it=0; it<16; ++it){
        int k  = it*8 + (t>>5);
        int n0 = (t&31)*4;
        fvec4 wv = *(const fvec4*)&W[(size_t)k*(D_*H_) + head*128 + n0];
        for (int i=0;i<4;++i) Ws[n0+i][k] = f2b(wv[i]);
    }
    __syncthreads();

    const int wave = t>>6, lane = t&63;
    const int wr = wave>>1, wc = wave&1;
    const int lrow = lane&15, lk8 = (lane>>4)*8;

    f32x4 acc[4][4] = {};
    for (int kc=0;kc<4;++kc){
        bf16x8 a[4], b[4];
        for (int mr=0;mr<4;++mr)
            a[mr] = asbf(*(const u16x8*)&xb[(size_t)(row0+wr*64+mr*16+lrow)*D_ + kc*32 + lk8]);
        for (int nr=0;nr<4;++nr)
            b[nr] = asbf(*(const u16x8*)&Ws[wc*64+nr*16+lrow][kc*32 + lk8]);
        for (int mr=0;mr<4;++mr)
            for (int nr=0;nr<4;++nr)
                acc[mr][nr] = MFMA(a[mr], b[nr], acc[mr][nr]);
    }

    const float qscale = 0.12751879455370425f;  // log2(e)/sqrt(128)
    for (int mr=0;mr<4;++mr){
        for (int nr=0;nr<4;++nr){
            f32x4 v = acc[mr][nr];
            int baserow = row0 + wr*64 + mr*16 + (lane>>4)*4;
            int cd = wc*64 + nr*16 + lrow;
            int b  = baserow / L_;
            int l  = baserow % L_;
            int bh = b*H_ + head;
            if (mat==2){
                u16x4 pv;
                for (int r=0;r<4;++r) pv[r] = f2b(v[r]);
                *(u16x4*)&v_ws[((size_t)bh*D_ + cd)*L_ + l] = pv;
            } else {
                u16* dst = (mat==0) ? q_ws : k_ws;
                for (int r=0;r<4;++r){
                    float f = v[r];
                    if (mat==0) f *= qscale;
                    dst[((size_t)bh*L_ + (l + r))*D_ + cd] = f2b(f);
                }
            }
        }
    }
}

// ---------------- kernel 2: flash attention, 32x32 MFMA, P fully in-register ----------------
// 512 blocks (XCD-bijective swizzle), 4 waves, wave owns 32 q rows.
// Swapped QK^T (mfma(K,Q)): lane owns one q-row -> softmax lane-local.
// P -> PV A-fragments assembled IN REGISTERS: pack bf16 pairs (v_cvt_pk) and
// exchange the complementary half-words with the hi-partner lane via
// __shfl_xor(32). No P LDS round-trip; loop has NO ds_writes (DMA only), so
// the per-tile barrier is raw vmcnt(0)+s_barrier (no lgkm drain).
__global__ __launch_bounds__(256)
void attn(const u16* __restrict__ q_ws, const u16* __restrict__ k_ws,
          const u16* __restrict__ v_ws, u16* __restrict__ o_ws)
{
    // XCD-bijective swizzle: 512 = 8*64
    const int wg = ((blockIdx.x & 7) << 6) | (blockIdx.x >> 3);
    const int qt = wg & 15;
    const int bh = wg >> 4;

    const int t = threadIdx.x, wave = t>>6, lane = t&63;
    const int q31 = lane & 31;     // operand row/col within 32
    const int hi  = lane >> 5;     // k-chunk selector
    const int swq = q31 & 7;

    __shared__ __align__(16) u16 Kb[2][64*128];  // [kv][d granules swizzled by kv&7]
    __shared__ __align__(16) u16 Vb[2][128*64];  // [d][kv granules swizzled by d&7]

    const int q0 = qt*128 + wave*32;

    // Q B-fragments (8 ksteps of K=16): lane holds Q[q0+q31][ks*16 + hi*8 .. +7]
    bf16x8 qf[8];
    #pragma unroll
    for (int ks=0; ks<8; ++ks)
        qf[ks] = asbf(*(const u16x8*)&q_ws[((size_t)bh*L_ + q0 + q31)*D_ + ks*16 + hi*8]);

    // staging: per-lane constant offsets, pointers advance 1 tile per call
    const u16* kp = k_ws + (size_t)bh*L_*D_;
    const u16* vp = v_ws + (size_t)bh*D_*L_;
    int koff[4], voff[4];
    #pragma unroll
    for (int i=0;i<4;++i){
        int f = i*256 + t;
        int kr = f>>4, kc = f&15;
        koff[i] = kr*128 + ((kc ^ (kr&7))*8);
        int vr = f>>3, vc = f&7;
        voff[i] = vr*L_ + ((vc ^ (vr&7))*8);
    }

    auto stage = [&](int buf){
        #pragma unroll
        for (int i=0;i<4;++i){
            gld16(kp + koff[i], &Kb[buf][(i*256 + wave*64)*8]);
            gld16(vp + voff[i], &Vb[buf][(i*256 + wave*64)*8]);
        }
        kp += 64*D_;   // next kv tile
        vp += 64;
    };

    float lsA = 0.f, lsB = 0.f;
    f32x16 o4[4] = {};

    stage(0);
    asm volatile("s_waitcnt vmcnt(0)" ::: "memory");
    __builtin_amdgcn_s_barrier();      // tile 0 resident

    for (int kt=0; kt<L_/64; ++kt){
        const int cur = kt & 1;
        if (kt < L_/64 - 1) stage(cur^1);   // async, completes at end-of-tile fence

        // S'[kv][q]: A = K rows, B = Q (log2e scale pre-folded into Q)
        f32x16 s0 = {}, s1 = {};
        __builtin_amdgcn_s_setprio(1);
        #pragma unroll
        for (int ks=0; ks<8; ++ks){
            bf16x8 ka = asbf(*(const u16x8*)&Kb[cur][q31*128 + (((ks*2+hi) ^ swq)*8)]);
            s0 = MFMA32(ka, qf[ks], s0);
        }
        #pragma unroll
        for (int ks=0; ks<8; ++ks){
            bf16x8 ka = asbf(*(const u16x8*)&Kb[cur][(32+q31)*128 + (((ks*2+hi) ^ swq)*8)]);
            s1 = MFMA32(ka, qf[ks], s1);
        }
        __builtin_amdgcn_s_setprio(0);

        // Per 16-kv chunk ks: P = 2^S' (lane-local row), pack to bf16 pairs,
        // exchange complementary words with partner lane (hi^1) via shfl_xor(32),
        // feed PV MFMAs immediately (PV(ks) overlaps softmax VALU of ks+1).
        // Own regs g -> kv offset (g&3) + 8*((g>>2)&1) + 4*hi within the chunk.
        #define SM_PV(SREG, KS) do { \
            float p0 = exp2f(SREG[((KS&1)*8)+0]); \
            float p1 = exp2f(SREG[((KS&1)*8)+1]); \
            float p2 = exp2f(SREG[((KS&1)*8)+2]); \
            float p3 = exp2f(SREG[((KS&1)*8)+3]); \
            float p4 = exp2f(SREG[((KS&1)*8)+4]); \
            float p5 = exp2f(SREG[((KS&1)*8)+5]); \
            float p6 = exp2f(SREG[((KS&1)*8)+6]); \
            float p7 = exp2f(SREG[((KS&1)*8)+7]); \
            lsA += (p0+p1)+(p2+p3); \
            lsB += (p4+p5)+(p6+p7); \
            uint32_t cA = pk2(p0,p1), cB = pk2(p2,p3); \
            uint32_t cC = pk2(p4,p5), cD = pk2(p6,p7); \
            uint32_t xA = (uint32_t)__shfl_xor((int)cA, 32, 64); \
            uint32_t xB = (uint32_t)__shfl_xor((int)cB, 32, 64); \
            uint32_t xC = (uint32_t)__shfl_xor((int)cC, 32, 64); \
            uint32_t xD = (uint32_t)__shfl_xor((int)cD, 32, 64); \
            u32x4 wv; \
            wv[0] = hi ? xC : cA;  wv[1] = hi ? xD : cB; \
            wv[2] = hi ? cC : xA;  wv[3] = hi ? cD : xB; \
            bf16x8 pa = __builtin_bit_cast(bf16x8, wv); \
            __builtin_amdgcn_s_setprio(1); \
            _Pragma("unroll") \
            for (int nc2=0; nc2<4; ++nc2){ \
                bf16x8 vb = asbf(*(const u16x8*)&Vb[cur][ (nc2*32+q31)*64 + (((KS*2+hi) ^ swq)*8) ]); \
                o4[nc2] = MFMA32(pa, vb, o4[nc2]); \
            } \
            __builtin_amdgcn_s_setprio(0); \
        } while(0)

        SM_PV(s0, 0);
        SM_PV(s0, 1);
        SM_PV(s1, 2);
        SM_PV(s1, 3);
        #undef SM_PV

        asm volatile("s_waitcnt vmcnt(0)" ::: "memory");  // next tile's DMA landed
        __builtin_amdgcn_s_barrier();                      // all waves done with buf[cur]
    }

    // finish row sums: halves split by hi -> one swap
    float lsum = lsA + lsB;
    lsum += __shfl_xor(lsum, 32, 64);
    float inv = 1.0f / lsum;   // lanes (q31, both hi) hold inv for q-row q31

    const int b = bh / H_, h = bh % H_;
    #pragma unroll
    for (int m=0; m<4; ++m){
        #pragma unroll
        for (int i=0; i<4; ++i){
            const int reg = m*4 + i;
            const int row = i + 8*m + 4*hi;         // C/D row pattern
            float riv = __shfl(inv, row, 64);       // bpermute from lane 'row'
            const int l = q0 + row;
            size_t base = ((size_t)(b*L_ + l))*(D_*H_) + h*128 + q31;
            #pragma unroll
            for (int nc2=0; nc2<4; ++nc2)
                o_ws[base + nc2*32] = f2b_native(o4[nc2][reg] * riv);
        }
    }
}

// ---------------- kernel 3: output projection + bias ----------------
__global__ __launch_bounds__(256)
void out_proj(const u16* __restrict__ o_ws, const float* __restrict__ Wu,
              const float* __restrict__ bu, float* __restrict__ out)
{
    const int rt = blockIdx.x;
    const int t = threadIdx.x, wave = t>>6, lane = t&63;
    const int lrow = lane&15, lgrp = lane>>4, lk8 = (lane>>4)*8;

    __shared__ __align__(16) u16 As[64][136];
    __shared__ __align__(16) u16 Wt[128][136];

    const int row0 = rt*64;
    f32x4 acc[8] = {};

    for (int ks=0; ks<8; ++ks){
        for (int it=0; it<4; ++it){
            int r = it*16 + (t>>4), k0 = (t&15)*8;
            *(u16x8*)&As[r][k0] = *(const u16x8*)&o_ws[(size_t)(row0+r)*(D_*H_) + ks*128 + k0];
        }
        for (int it=0; it<16; ++it){
            int k  = it*8 + (t>>5);
            int n0 = (t&31)*4;
            fvec4 wv = *(const fvec4*)&Wu[(size_t)(ks*128 + k)*D_ + n0];
            for (int i=0;i<4;++i) Wt[n0+i][k] = f2b(wv[i]);
        }
        __syncthreads();

        for (int kc=0;kc<4;++kc){
            bf16x8 a = asbf(*(const u16x8*)&As[wave*16+lrow][kc*32 + lk8]);
            for (int nc=0;nc<8;++nc){
                bf16x8 b = asbf(*(const u16x8*)&Wt[nc*16+lrow][kc*32 + lk8]);
                acc[nc] = MFMA(a, b, acc[nc]);
            }
        }
        __syncthreads();
    }

    for (int nc=0;nc<8;++nc){
        for (int r=0;r<4;++r){
            int row = row0 + wave*16 + lgrp*4 + r;
            int n = nc*16 + lrow;
            out[(size_t)row*D_ + n] = acc[nc][r] + bu[n];
        }
    }
}

// ---------------- launcher ----------------
extern "C" void kernel_launch(void* const* d_in, const int* in_sizes, int n_in,
                              void* d_out, int out_size, void* d_ws, size_t ws_size,
                              hipStream_t stream)
{
    const float* x  = (const float*)d_in[0];
    const float* Wq = (const float*)d_in[1];
    const float* Wk = (const float*)d_in[2];
    const float* Wv = (const float*)d_in[3];
    const float* Wu = (const float*)d_in[4];
    const float* bu = (const float*)d_in[5];
    float* out = (float*)d_out;

    u16* ws = (u16*)d_ws;
    const size_t SZ = (size_t)NH * L_ * D_;
    u16* q_ws = ws;
    u16* k_ws = q_ws + SZ;
    u16* v_ws = k_ws + SZ;
    u16* o_ws = v_ws + SZ;
    u16* x_bf = o_ws + SZ;

    cvt_x<<<dim3((B_*L_*D_)/(256*8)), 256, 0, stream>>>(x, x_bf);
    qkv_proj<<<dim3(H_, (B_*L_)/128, 3), 256, 0, stream>>>(x_bf, Wq, Wk, Wv, q_ws, k_ws, v_ws);
    attn<<<dim3((L_/128)*NH), 256, 0, stream>>>(q_ws, k_ws, v_ws, o_ws);
    out_proj<<<dim3((B_*L_)/64), 256, 0, stream>>>(o_ws, Wu, bu, out);
}

// Round 9
// 184.642 us; speedup vs baseline: 1.0257x; 1.0257x over previous
//
#include <hip/hip_runtime.h>
#include <stdint.h>

#define D_ 128
#define H_ 8
#define B_ 4
#define L_ 2048
#define NH (B_*H_)

typedef __bf16 bf16x8 __attribute__((ext_vector_type(8)));
typedef float f32x4 __attribute__((ext_vector_type(4)));
typedef float f32x16 __attribute__((ext_vector_type(16)));
typedef unsigned short u16;
typedef u16 u16x2 __attribute__((ext_vector_type(2)));
typedef u16 u16x4 __attribute__((ext_vector_type(4)));
typedef u16 u16x8 __attribute__((ext_vector_type(8)));
typedef uint32_t u32x4 __attribute__((ext_vector_type(4)));
typedef float fvec4 __attribute__((ext_vector_type(4)));

__device__ __forceinline__ u16 f2b(float f){
    uint32_t u = __builtin_bit_cast(uint32_t, f);
    u += 0x7fffu + ((u >> 16) & 1u);
    return (u16)(u >> 16);
}
__device__ __forceinline__ u16 f2b_native(float f){
    return __builtin_bit_cast(u16, (__bf16)f);
}
// pack 2 f32 -> u32 of 2 bf16 (compiler emits v_cvt_pk_bf16_f32)
__device__ __forceinline__ uint32_t pk2(float a, float b){
    u16x2 v = { f2b_native(a), f2b_native(b) };
    return __builtin_bit_cast(uint32_t, v);
}
__device__ __forceinline__ bf16x8 asbf(u16x8 v){ return __builtin_bit_cast(bf16x8, v); }
#define MFMA(a,b,c)   __builtin_amdgcn_mfma_f32_16x16x32_bf16((a),(b),(c),0,0,0)
#define MFMA32(a,b,c) __builtin_amdgcn_mfma_f32_32x32x16_bf16((a),(b),(c),0,0,0)

// async global->LDS, 16B per lane; LDS dest is wave-uniform base + lane*16
__device__ __forceinline__ void gld16(const u16* g, u16* l){
    __builtin_amdgcn_global_load_lds(
        (const __attribute__((address_space(1))) void*)g,
        (__attribute__((address_space(3))) void*)l, 16, 0, 0);
}

// ---------------- kernel 0: convert x fp32 -> bf16 ----------------
__global__ __launch_bounds__(256)
void cvt_x(const float* __restrict__ x, u16* __restrict__ xb){
    size_t i = ((size_t)blockIdx.x*256 + threadIdx.x)*8;
    fvec4 lo = *(const fvec4*)&x[i];
    fvec4 hi = *(const fvec4*)&x[i+4];
    u16x8 u;
    for (int j=0;j<4;++j){ u[j]=f2b(lo[j]); u[4+j]=f2b(hi[j]); }
    *(u16x8*)&xb[i] = u;
}

// ---------------- kernel 1: QKV projection ----------------
// Q: q_ws[bh][l][d] (pre-scaled by log2e/sqrt(D)), K: k_ws[bh][l][d], V: v_ws[bh][d][l]
__global__ __launch_bounds__(256)
void qkv_proj(const u16* __restrict__ xb,
              const float* __restrict__ Wq, const float* __restrict__ Wk, const float* __restrict__ Wv,
              u16* __restrict__ q_ws, u16* __restrict__ k_ws, u16* __restrict__ v_ws)
{
    const int head = blockIdx.x;
    const int rt   = blockIdx.y;
    const int mat  = blockIdx.z;
    const float* W = (mat==0) ? Wq : ((mat==1) ? Wk : Wv);

    __shared__ __align__(16) u16 Ws[128][136];

    const int t = threadIdx.x;
    const int row0 = rt*128;

    for (int it=0; it<16; ++it){
        int k  = it*8 + (t>>5);
        int n0 = (t&31)*4;
        fvec4 wv = *(const fvec4*)&W[(size_t)k*(D_*H_) + head*128 + n0];
        for (int i=0;i<4;++i) Ws[n0+i][k] = f2b(wv[i]);
    }
    __syncthreads();

    const int wave = t>>6, lane = t&63;
    const int wr = wave>>1, wc = wave&1;
    const int lrow = lane&15, lk8 = (lane>>4)*8;

    f32x4 acc[4][4] = {};
    for (int kc=0;kc<4;++kc){
        bf16x8 a[4], b[4];
        for (int mr=0;mr<4;++mr)
            a[mr] = asbf(*(const u16x8*)&xb[(size_t)(row0+wr*64+mr*16+lrow)*D_ + kc*32 + lk8]);
        for (int nr=0;nr<4;++nr)
            b[nr] = asbf(*(const u16x8*)&Ws[wc*64+nr*16+lrow][kc*32 + lk8]);
        for (int mr=0;mr<4;++mr)
            for (int nr=0;nr<4;++nr)
                acc[mr][nr] = MFMA(a[mr], b[nr], acc[mr][nr]);
    }

    const float qscale = 0.12751879455370425f;  // log2(e)/sqrt(128)
    for (int mr=0;mr<4;++mr){
        for (int nr=0;nr<4;++nr){
            f32x4 v = acc[mr][nr];
            int baserow = row0 + wr*64 + mr*16 + (lane>>4)*4;
            int cd = wc*64 + nr*16 + lrow;
            int b  = baserow / L_;
            int l  = baserow % L_;
            int bh = b*H_ + head;
            if (mat==2){
                u16x4 pv;
                for (int r=0;r<4;++r) pv[r] = f2b(v[r]);
                *(u16x4*)&v_ws[((size_t)bh*D_ + cd)*L_ + l] = pv;
            } else {
                u16* dst = (mat==0) ? q_ws : k_ws;
                for (int r=0;r<4;++r){
                    float f = v[r];
                    if (mat==0) f *= qscale;
                    dst[((size_t)bh*L_ + (l + r))*D_ + cd] = f2b(f);
                }
            }
        }
    }
}

// ---------------- kernel 2: flash attention, counted-vmcnt pipeline (T3+T4) ----------------
// 256 blocks (1/CU) x 512 threads (8 waves); wave owns 32 q rows; q-tile 256.
// 3-deep K/V LDS ring, 2-tiles-ahead DMA prefetch. Per tile: issue stage(t+2),
// compute (no intra-tile barriers; buffer complete before tile starts),
// fence = vmcnt(4) [stage(t+1) landed, t+2 still in flight] + ONE barrier.
// Never drains vmcnt to 0 in steady state (T4).
// Swapped QK^T (mfma(K,Q)) -> lane-local softmax; P in-register via pk2+shfl_xor(32).
__global__ __launch_bounds__(512)
void attn(const u16* __restrict__ q_ws, const u16* __restrict__ k_ws,
          const u16* __restrict__ v_ws, u16* __restrict__ o_ws)
{
    // XCD-bijective swizzle: 256 = 8*32
    const int wg = ((blockIdx.x & 7) << 5) | (blockIdx.x >> 3);
    const int qt = wg & 7;
    const int bh = wg >> 3;

    const int t = threadIdx.x, wave = t>>6, lane = t&63;
    const int q31 = lane & 31;     // operand row/col within 32
    const int hi  = lane >> 5;     // k-chunk selector
    const int swq = q31 & 7;

    __shared__ __align__(16) u16 Kb[3][64*128];  // [kv][d granules swizzled by kv&7]
    __shared__ __align__(16) u16 Vb[3][128*64];  // [d][kv granules swizzled by d&7]

    const int q0 = qt*256 + wave*32;

    // Q B-fragments (8 ksteps of K=16): lane holds Q[q0+q31][ks*16 + hi*8 .. +7]
    bf16x8 qf[8];
    #pragma unroll
    for (int ks=0; ks<8; ++ks)
        qf[ks] = asbf(*(const u16x8*)&q_ws[((size_t)bh*L_ + q0 + q31)*D_ + ks*16 + hi*8]);

    // staging: 512 threads, 2 rounds each for K (1024 granules) and V
    const u16* kp = k_ws + (size_t)bh*L_*D_;
    const u16* vp = v_ws + (size_t)bh*D_*L_;
    int koff[2], voff[2];
    #pragma unroll
    for (int i=0;i<2;++i){
        int f = i*512 + t;
        int kr = f>>4, kc = f&15;
        koff[i] = kr*128 + ((kc ^ (kr&7))*8);
        int vr = f>>3, vc = f&7;
        voff[i] = vr*L_ + ((vc ^ (vr&7))*8);
    }

    auto stage = [&](int buf){   // 4 DMA per wave per call
        #pragma unroll
        for (int i=0;i<2;++i){
            gld16(kp + koff[i], &Kb[buf][(i*512 + wave*64)*8]);
            gld16(vp + voff[i], &Vb[buf][(i*512 + wave*64)*8]);
        }
        kp += 64*D_;   // next kv tile
        vp += 64;
    };

    float lsA = 0.f, lsB = 0.f;
    f32x16 o4[4] = {};

    stage(0);                                       // 4 in flight
    stage(1);                                       // 8 in flight
    asm volatile("s_waitcnt vmcnt(4)" ::: "memory"); // tile 0 landed
    __builtin_amdgcn_s_barrier();

    for (int kt=0; kt<L_/64; ++kt){
        const int cur = kt % 3;
        if (kt < L_/64 - 2) stage((kt+2) % 3);      // overwrites buf last read in kt-1 (post-barrier: safe)

        // S'[kv][q]: A = K rows, B = Q (log2e scale pre-folded into Q)
        f32x16 s0 = {}, s1 = {};
        __builtin_amdgcn_s_setprio(1);
        #pragma unroll
        for (int ks=0; ks<8; ++ks){
            bf16x8 ka = asbf(*(const u16x8*)&Kb[cur][q31*128 + (((ks*2+hi) ^ swq)*8)]);
            s0 = MFMA32(ka, qf[ks], s0);
        }
        #pragma unroll
        for (int ks=0; ks<8; ++ks){
            bf16x8 ka = asbf(*(const u16x8*)&Kb[cur][(32+q31)*128 + (((ks*2+hi) ^ swq)*8)]);
            s1 = MFMA32(ka, qf[ks], s1);
        }
        __builtin_amdgcn_s_setprio(0);

        // Per 16-kv chunk: P = 2^S' (lane-local row), pack bf16 pairs, exchange
        // complementary words with hi-partner via shfl_xor(32), feed PV MFMAs.
        #define SM_PV(SREG, KS) do { \
            float p0 = exp2f(SREG[((KS&1)*8)+0]); \
            float p1 = exp2f(SREG[((KS&1)*8)+1]); \
            float p2 = exp2f(SREG[((KS&1)*8)+2]); \
            float p3 = exp2f(SREG[((KS&1)*8)+3]); \
            float p4 = exp2f(SREG[((KS&1)*8)+4]); \
            float p5 = exp2f(SREG[((KS&1)*8)+5]); \
            float p6 = exp2f(SREG[((KS&1)*8)+6]); \
            float p7 = exp2f(SREG[((KS&1)*8)+7]); \
            lsA += (p0+p1)+(p2+p3); \
            lsB += (p4+p5)+(p6+p7); \
            uint32_t cA = pk2(p0,p1), cB = pk2(p2,p3); \
            uint32_t cC = pk2(p4,p5), cD = pk2(p6,p7); \
            uint32_t xA = (uint32_t)__shfl_xor((int)cA, 32, 64); \
            uint32_t xB = (uint32_t)__shfl_xor((int)cB, 32, 64); \
            uint32_t xC = (uint32_t)__shfl_xor((int)cC, 32, 64); \
            uint32_t xD = (uint32_t)__shfl_xor((int)cD, 32, 64); \
            u32x4 wv; \
            wv[0] = hi ? xC : cA;  wv[1] = hi ? xD : cB; \
            wv[2] = hi ? cC : xA;  wv[3] = hi ? cD : xB; \
            bf16x8 pa = __builtin_bit_cast(bf16x8, wv); \
            __builtin_amdgcn_s_setprio(1); \
            _Pragma("unroll") \
            for (int nc2=0; nc2<4; ++nc2){ \
                bf16x8 vb = asbf(*(const u16x8*)&Vb[cur][ (nc2*32+q31)*64 + (((KS*2+hi) ^ swq)*8) ]); \
                o4[nc2] = MFMA32(pa, vb, o4[nc2]); \
            } \
            __builtin_amdgcn_s_setprio(0); \
        } while(0)

        SM_PV(s0, 0);
        SM_PV(s0, 1);
        SM_PV(s1, 2);
        SM_PV(s1, 3);
        #undef SM_PV

        // tile-end fence: counted vmcnt (stage(kt+1) landed; stage(kt+2) may fly)
        if (kt < L_/64 - 1){
            if (kt < L_/64 - 2) asm volatile("s_waitcnt vmcnt(4)" ::: "memory");
            else                asm volatile("s_waitcnt vmcnt(0)" ::: "memory");
            __builtin_amdgcn_s_barrier();
        }
    }

    // finish row sums: halves split by hi -> one swap
    float lsum = lsA + lsB;
    lsum += __shfl_xor(lsum, 32, 64);
    float inv = 1.0f / lsum;   // lanes (q31, both hi) hold inv for q-row q31

    const int b = bh / H_, h = bh % H_;
    #pragma unroll
    for (int m=0; m<4; ++m){
        #pragma unroll
        for (int i=0; i<4; ++i){
            const int reg = m*4 + i;
            const int row = i + 8*m + 4*hi;         // C/D row pattern
            float riv = __shfl(inv, row, 64);       // bpermute from lane 'row'
            const int l = q0 + row;
            size_t base = ((size_t)(b*L_ + l))*(D_*H_) + h*128 + q31;
            #pragma unroll
            for (int nc2=0; nc2<4; ++nc2)
                o_ws[base + nc2*32] = f2b_native(o4[nc2][reg] * riv);
        }
    }
}

// ---------------- kernel 3: output projection + bias ----------------
__global__ __launch_bounds__(256)
void out_proj(const u16* __restrict__ o_ws, const float* __restrict__ Wu,
              const float* __restrict__ bu, float* __restrict__ out)
{
    const int rt = blockIdx.x;
    const int t = threadIdx.x, wave = t>>6, lane = t&63;
    const int lrow = lane&15, lgrp = lane>>4, lk8 = (lane>>4)*8;

    __shared__ __align__(16) u16 As[64][136];
    __shared__ __align__(16) u16 Wt[128][136];

    const int row0 = rt*64;
    f32x4 acc[8] = {};

    for (int ks=0; ks<8; ++ks){
        for (int it=0; it<4; ++it){
            int r = it*16 + (t>>4), k0 = (t&15)*8;
            *(u16x8*)&As[r][k0] = *(const u16x8*)&o_ws[(size_t)(row0+r)*(D_*H_) + ks*128 + k0];
        }
        for (int it=0; it<16; ++it){
            int k  = it*8 + (t>>5);
            int n0 = (t&31)*4;
            fvec4 wv = *(const fvec4*)&Wu[(size_t)(ks*128 + k)*D_ + n0];
            for (int i=0;i<4;++i) Wt[n0+i][k] = f2b(wv[i]);
        }
        __syncthreads();

        for (int kc=0;kc<4;++kc){
            bf16x8 a = asbf(*(const u16x8*)&As[wave*16+lrow][kc*32 + lk8]);
            for (int nc=0;nc<8;++nc){
                bf16x8 b = asbf(*(const u16x8*)&Wt[nc*16+lrow][kc*32 + lk8]);
                acc[nc] = MFMA(a, b, acc[nc]);
            }
        }
        __syncthreads();
    }

    for (int nc=0;nc<8;++nc){
        for (int r=0;r<4;++r){
            int row = row0 + wave*16 + lgrp*4 + r;
            int n = nc*16 + lrow;
            out[(size_t)row*D_ + n] = acc[nc][r] + bu[n];
        }
    }
}

// ---------------- launcher ----------------
extern "C" void kernel_launch(void* const* d_in, const int* in_sizes, int n_in,
                              void* d_out, int out_size, void* d_ws, size_t ws_size,
                              hipStream_t stream)
{
    const float* x  = (const float*)d_in[0];
    const float* Wq = (const float*)d_in[1];
    const float* Wk = (const float*)d_in[2];
    const float* Wv = (const float*)d_in[3];
    const float* Wu = (const float*)d_in[4];
    const float* bu = (const float*)d_in[5];
    float* out = (float*)d_out;

    u16* ws = (u16*)d_ws;
    const size_t SZ = (size_t)NH * L_ * D_;
    u16* q_ws = ws;
    u16* k_ws = q_ws + SZ;
    u16* v_ws = k_ws + SZ;
    u16* o_ws = v_ws + SZ;
    u16* x_bf = o_ws + SZ;

    cvt_x<<<dim3((B_*L_*D_)/(256*8)), 256, 0, stream>>>(x, x_bf);
    qkv_proj<<<dim3(H_, (B_*L_)/128, 3), 256, 0, stream>>>(x_bf, Wq, Wk, Wv, q_ws, k_ws, v_ws);
    attn<<<dim3((L_/256)*NH), 512, 0, stream>>>(q_ws, k_ws, v_ws, o_ws);
    out_proj<<<dim3((B_*L_)/64), 256, 0, stream>>>(o_ws, Wu, bu, out);
}

// Round 10
// 169.706 us; speedup vs baseline: 1.1160x; 1.0880x over previous
//
#include <hip/hip_runtime.h>
#include <stdint.h>

#define D_ 128
#define H_ 8
#define B_ 4
#define L_ 2048
#define NH (B_*H_)

typedef __bf16 bf16x8 __attribute__((ext_vector_type(8)));
typedef float f32x4 __attribute__((ext_vector_type(4)));
typedef float f32x16 __attribute__((ext_vector_type(16)));
typedef unsigned short u16;
typedef u16 u16x2 __attribute__((ext_vector_type(2)));
typedef u16 u16x4 __attribute__((ext_vector_type(4)));
typedef u16 u16x8 __attribute__((ext_vector_type(8)));
typedef uint32_t u32x2 __attribute__((ext_vector_type(2)));
typedef uint32_t u32x4 __attribute__((ext_vector_type(4)));
typedef float fvec4 __attribute__((ext_vector_type(4)));

__device__ __forceinline__ u16 f2b(float f){
    uint32_t u = __builtin_bit_cast(uint32_t, f);
    u += 0x7fffu + ((u >> 16) & 1u);
    return (u16)(u >> 16);
}
__device__ __forceinline__ u16 f2b_native(float f){
    return __builtin_bit_cast(u16, (__bf16)f);
}
// pack 2 f32 -> u32 of 2 bf16 (compiler emits v_cvt_pk_bf16_f32)
__device__ __forceinline__ uint32_t pk2(float a, float b){
    u16x2 v = { f2b_native(a), f2b_native(b) };
    return __builtin_bit_cast(uint32_t, v);
}
// raw 2^x
__device__ __forceinline__ float ex2(float x){
#if __has_builtin(__builtin_amdgcn_exp2f)
    return __builtin_amdgcn_exp2f(x);
#else
    return exp2f(x);
#endif
}
// v_permlane32_swap_b32: r[0] = {a.lo16lanes.., b.lo}, r[1] = {a.hi, b.hi}
// (lanes<32 of r[0] = own a; lanes>=32 of r[0] = partner's b; lanes<32 of r[1] =
//  partner's a; lanes>=32 of r[1] = own b)
__device__ __forceinline__ u32x2 permswap(uint32_t a, uint32_t b){
#if __has_builtin(__builtin_amdgcn_permlane32_swap)
    return __builtin_amdgcn_permlane32_swap(a, b, false, false);
#else
    asm volatile("v_permlane32_swap_b32 %0, %1" : "+v"(a), "+v"(b));
    u32x2 r; r[0] = a; r[1] = b; return r;
#endif
}
__device__ __forceinline__ bf16x8 asbf(u16x8 v){ return __builtin_bit_cast(bf16x8, v); }
#define MFMA(a,b,c)   __builtin_amdgcn_mfma_f32_16x16x32_bf16((a),(b),(c),0,0,0)
#define MFMA32(a,b,c) __builtin_amdgcn_mfma_f32_32x32x16_bf16((a),(b),(c),0,0,0)

// async global->LDS, 16B per lane; LDS dest is wave-uniform base + lane*16
__device__ __forceinline__ void gld16(const u16* g, u16* l){
    __builtin_amdgcn_global_load_lds(
        (const __attribute__((address_space(1))) void*)g,
        (__attribute__((address_space(3))) void*)l, 16, 0, 0);
}

// ---------------- kernel 0: convert x fp32 -> bf16 ----------------
__global__ __launch_bounds__(256)
void cvt_x(const float* __restrict__ x, u16* __restrict__ xb){
    size_t i = ((size_t)blockIdx.x*256 + threadIdx.x)*8;
    fvec4 lo = *(const fvec4*)&x[i];
    fvec4 hi = *(const fvec4*)&x[i+4];
    u16x8 u;
    for (int j=0;j<4;++j){ u[j]=f2b(lo[j]); u[4+j]=f2b(hi[j]); }
    *(u16x8*)&xb[i] = u;
}

// ---------------- kernel 1: QKV projection ----------------
// Q: q_ws[bh][l][d] (pre-scaled by log2e/sqrt(D)), K: k_ws[bh][l][d], V: v_ws[bh][d][l]
__global__ __launch_bounds__(256)
void qkv_proj(const u16* __restrict__ xb,
              const float* __restrict__ Wq, const float* __restrict__ Wk, const float* __restrict__ Wv,
              u16* __restrict__ q_ws, u16* __restrict__ k_ws, u16* __restrict__ v_ws)
{
    const int head = blockIdx.x;
    const int rt   = blockIdx.y;
    const int mat  = blockIdx.z;
    const float* W = (mat==0) ? Wq : ((mat==1) ? Wk : Wv);

    __shared__ __align__(16) u16 Ws[128][136];

    const int t = threadIdx.x;
    const int row0 = rt*128;

    for (int it=0; it<16; ++it){
        int k  = it*8 + (t>>5);
        int n0 = (t&31)*4;
        fvec4 wv = *(const fvec4*)&W[(size_t)k*(D_*H_) + head*128 + n0];
        for (int i=0;i<4;++i) Ws[n0+i][k] = f2b(wv[i]);
    }
    __syncthreads();

    const int wave = t>>6, lane = t&63;
    const int wr = wave>>1, wc = wave&1;
    const int lrow = lane&15, lk8 = (lane>>4)*8;

    f32x4 acc[4][4] = {};
    for (int kc=0;kc<4;++kc){
        bf16x8 a[4], b[4];
        for (int mr=0;mr<4;++mr)
            a[mr] = asbf(*(const u16x8*)&xb[(size_t)(row0+wr*64+mr*16+lrow)*D_ + kc*32 + lk8]);
        for (int nr=0;nr<4;++nr)
            b[nr] = asbf(*(const u16x8*)&Ws[wc*64+nr*16+lrow][kc*32 + lk8]);
        for (int mr=0;mr<4;++mr)
            for (int nr=0;nr<4;++nr)
                acc[mr][nr] = MFMA(a[mr], b[nr], acc[mr][nr]);
    }

    const float qscale = 0.12751879455370425f;  // log2(e)/sqrt(128)
    for (int mr=0;mr<4;++mr){
        for (int nr=0;nr<4;++nr){
            f32x4 v = acc[mr][nr];
            int baserow = row0 + wr*64 + mr*16 + (lane>>4)*4;
            int cd = wc*64 + nr*16 + lrow;
            int b  = baserow / L_;
            int l  = baserow % L_;
            int bh = b*H_ + head;
            if (mat==2){
                u16x4 pv;
                for (int r=0;r<4;++r) pv[r] = f2b(v[r]);
                *(u16x4*)&v_ws[((size_t)bh*D_ + cd)*L_ + l] = pv;
            } else {
                u16* dst = (mat==0) ? q_ws : k_ws;
                for (int r=0;r<4;++r){
                    float f = v[r];
                    if (mat==0) f *= qscale;
                    dst[((size_t)bh*L_ + (l + r))*D_ + cd] = f2b(f);
                }
            }
        }
    }
}

// ---------------- kernel 2: flash attention ----------------
// 256 blocks (1/CU) x 512 threads (8 waves); wave owns 32 q rows; q-tile 256.
// 3-deep K/V LDS ring, 2-tiles-ahead DMA prefetch, counted vmcnt fence.
// Swapped QK^T (mfma(K,Q)) with 4-way split accumulators (ILP on the MFMA
// latency chain). Softmax lane-local; P exchanged across lane-halves with
// v_permlane32_swap_b32 (2 VALU ops/chunk, replaces 4 ds_bpermute + 8 selects).
__global__ __launch_bounds__(512)
void attn(const u16* __restrict__ q_ws, const u16* __restrict__ k_ws,
          const u16* __restrict__ v_ws, u16* __restrict__ o_ws)
{
    // XCD-bijective swizzle: 256 = 8*32
    const int wg = ((blockIdx.x & 7) << 5) | (blockIdx.x >> 3);
    const int qt = wg & 7;
    const int bh = wg >> 3;

    const int t = threadIdx.x, wave = t>>6, lane = t&63;
    const int q31 = lane & 31;     // operand row/col within 32
    const int hi  = lane >> 5;     // k-chunk selector
    const int swq = q31 & 7;

    __shared__ __align__(16) u16 Kb[3][64*128];  // [kv][d granules swizzled by kv&7]
    __shared__ __align__(16) u16 Vb[3][128*64];  // [d][kv granules swizzled by d&7]

    const int q0 = qt*256 + wave*32;

    // Q B-fragments (8 ksteps of K=16): lane holds Q[q0+q31][ks*16 + hi*8 .. +7]
    bf16x8 qf[8];
    #pragma unroll
    for (int ks=0; ks<8; ++ks)
        qf[ks] = asbf(*(const u16x8*)&q_ws[((size_t)bh*L_ + q0 + q31)*D_ + ks*16 + hi*8]);

    // staging: 512 threads, 2 rounds each for K (1024 granules) and V
    const u16* kp = k_ws + (size_t)bh*L_*D_;
    const u16* vp = v_ws + (size_t)bh*D_*L_;
    int koff[2], voff[2];
    #pragma unroll
    for (int i=0;i<2;++i){
        int f = i*512 + t;
        int kr = f>>4, kc = f&15;
        koff[i] = kr*128 + ((kc ^ (kr&7))*8);
        int vr = f>>3, vc = f&7;
        voff[i] = vr*L_ + ((vc ^ (vr&7))*8);
    }

    auto stage = [&](int buf){   // 4 DMA per wave per call
        #pragma unroll
        for (int i=0;i<2;++i){
            gld16(kp + koff[i], &Kb[buf][(i*512 + wave*64)*8]);
            gld16(vp + voff[i], &Vb[buf][(i*512 + wave*64)*8]);
        }
        kp += 64*D_;   // next kv tile
        vp += 64;
    };

    float lsA = 0.f, lsB = 0.f;
    f32x16 o4[4] = {};

    stage(0);                                       // 4 in flight
    stage(1);                                       // 8 in flight
    asm volatile("s_waitcnt vmcnt(4)" ::: "memory"); // tile 0 landed
    __builtin_amdgcn_s_barrier();

    for (int kt=0; kt<L_/64; ++kt){
        const int cur = kt % 3;
        if (kt < L_/64 - 2) stage((kt+2) % 3);

        // S'[kv][q]: A = K rows, B = Q. 4 independent accumulate chains.
        f32x16 s0a = {}, s0b = {}, s1a = {}, s1b = {};
        __builtin_amdgcn_s_setprio(1);
        #pragma unroll
        for (int ks=0; ks<4; ++ks){
            bf16x8 ka0 = asbf(*(const u16x8*)&Kb[cur][q31*128      + (((ks*2+hi)     ^ swq)*8)]);
            bf16x8 ka1 = asbf(*(const u16x8*)&Kb[cur][q31*128      + ((((ks+4)*2+hi) ^ swq)*8)]);
            bf16x8 kb0 = asbf(*(const u16x8*)&Kb[cur][(32+q31)*128 + (((ks*2+hi)     ^ swq)*8)]);
            bf16x8 kb1 = asbf(*(const u16x8*)&Kb[cur][(32+q31)*128 + ((((ks+4)*2+hi) ^ swq)*8)]);
            s0a = MFMA32(ka0, qf[ks],   s0a);
            s0b = MFMA32(ka1, qf[ks+4], s0b);
            s1a = MFMA32(kb0, qf[ks],   s1a);
            s1b = MFMA32(kb1, qf[ks+4], s1b);
        }
        __builtin_amdgcn_s_setprio(0);
        f32x16 s0 = s0a + s0b;
        f32x16 s1 = s1a + s1b;

        // Per 16-kv chunk: P = 2^S' (lane-local row), pack bf16 pairs, exchange
        // across lane-halves with permlane32_swap, feed PV MFMAs.
        // swap(cA,cC): r[0] -> wv[0], r[1] -> wv[2] valid for BOTH halves.
        #define SM_PV(SREG, KS) do { \
            float p0 = ex2(SREG[((KS&1)*8)+0]); \
            float p1 = ex2(SREG[((KS&1)*8)+1]); \
            float p2 = ex2(SREG[((KS&1)*8)+2]); \
            float p3 = ex2(SREG[((KS&1)*8)+3]); \
            float p4 = ex2(SREG[((KS&1)*8)+4]); \
            float p5 = ex2(SREG[((KS&1)*8)+5]); \
            float p6 = ex2(SREG[((KS&1)*8)+6]); \
            float p7 = ex2(SREG[((KS&1)*8)+7]); \
            lsA += (p0+p1)+(p2+p3); \
            lsB += (p4+p5)+(p6+p7); \
            uint32_t cA = pk2(p0,p1), cB = pk2(p2,p3); \
            uint32_t cC = pk2(p4,p5), cD = pk2(p6,p7); \
            u32x2 r0 = permswap(cA, cC); \
            u32x2 r1 = permswap(cB, cD); \
            u32x4 wv; \
            wv[0] = r0[0];  wv[1] = r1[0]; \
            wv[2] = r0[1];  wv[3] = r1[1]; \
            bf16x8 pa = __builtin_bit_cast(bf16x8, wv); \
            __builtin_amdgcn_s_setprio(1); \
            _Pragma("unroll") \
            for (int nc2=0; nc2<4; ++nc2){ \
                bf16x8 vb = asbf(*(const u16x8*)&Vb[cur][ (nc2*32+q31)*64 + (((KS*2+hi) ^ swq)*8) ]); \
                o4[nc2] = MFMA32(pa, vb, o4[nc2]); \
            } \
            __builtin_amdgcn_s_setprio(0); \
        } while(0)

        SM_PV(s0, 0);
        SM_PV(s0, 1);
        SM_PV(s1, 2);
        SM_PV(s1, 3);
        #undef SM_PV

        // tile-end fence: counted vmcnt (stage(kt+1) landed; stage(kt+2) may fly)
        if (kt < L_/64 - 1){
            if (kt < L_/64 - 2) asm volatile("s_waitcnt vmcnt(4)" ::: "memory");
            else                asm volatile("s_waitcnt vmcnt(0)" ::: "memory");
            __builtin_amdgcn_s_barrier();
        }
    }

    // finish row sums: halves split by hi -> one swap
    float lsum = lsA + lsB;
    lsum += __shfl_xor(lsum, 32, 64);
    float inv = 1.0f / lsum;   // lanes (q31, both hi) hold inv for q-row q31

    const int b = bh / H_, h = bh % H_;
    #pragma unroll
    for (int m=0; m<4; ++m){
        #pragma unroll
        for (int i=0; i<4; ++i){
            const int reg = m*4 + i;
            const int row = i + 8*m + 4*hi;         // C/D row pattern
            float riv = __shfl(inv, row, 64);       // bpermute from lane 'row'
            const int l = q0 + row;
            size_t base = ((size_t)(b*L_ + l))*(D_*H_) + h*128 + q31;
            #pragma unroll
            for (int nc2=0; nc2<4; ++nc2)
                o_ws[base + nc2*32] = f2b_native(o4[nc2][reg] * riv);
        }
    }
}

// ---------------- kernel 3: output projection + bias ----------------
__global__ __launch_bounds__(256)
void out_proj(const u16* __restrict__ o_ws, const float* __restrict__ Wu,
              const float* __restrict__ bu, float* __restrict__ out)
{
    const int rt = blockIdx.x;
    const int t = threadIdx.x, wave = t>>6, lane = t&63;
    const int lrow = lane&15, lgrp = lane>>4, lk8 = (lane>>4)*8;

    __shared__ __align__(16) u16 As[64][136];
    __shared__ __align__(16) u16 Wt[128][136];

    const int row0 = rt*64;
    f32x4 acc[8] = {};

    for (int ks=0; ks<8; ++ks){
        for (int it=0; it<4; ++it){
            int r = it*16 + (t>>4), k0 = (t&15)*8;
            *(u16x8*)&As[r][k0] = *(const u16x8*)&o_ws[(size_t)(row0+r)*(D_*H_) + ks*128 + k0];
        }
        for (int it=0; it<16; ++it){
            int k  = it*8 + (t>>5);
            int n0 = (t&31)*4;
            fvec4 wv = *(const fvec4*)&Wu[(size_t)(ks*128 + k)*D_ + n0];
            for (int i=0;i<4;++i) Wt[n0+i][k] = f2b(wv[i]);
        }
        __syncthreads();

        for (int kc=0;kc<4;++kc){
            bf16x8 a = asbf(*(const u16x8*)&As[wave*16+lrow][kc*32 + lk8]);
            for (int nc=0;nc<8;++nc){
                bf16x8 b = asbf(*(const u16x8*)&Wt[nc*16+lrow][kc*32 + lk8]);
                acc[nc] = MFMA(a, b, acc[nc]);
            }
        }
        __syncthreads();
    }

    for (int nc=0;nc<8;++nc){
        for (int r=0;r<4;++r){
            int row = row0 + wave*16 + lgrp*4 + r;
            int n = nc*16 + lrow;
            out[(size_t)row*D_ + n] = acc[nc][r] + bu[n];
        }
    }
}

// ---------------- launcher ----------------
extern "C" void kernel_launch(void* const* d_in, const int* in_sizes, int n_in,
                              void* d_out, int out_size, void* d_ws, size_t ws_size,
                              hipStream_t stream)
{
    const float* x  = (const float*)d_in[0];
    const float* Wq = (const float*)d_in[1];
    const float* Wk = (const float*)d_in[2];
    const float* Wv = (const float*)d_in[3];
    const float* Wu = (const float*)d_in[4];
    const float* bu = (const float*)d_in[5];
    float* out = (float*)d_out;

    u16* ws = (u16*)d_ws;
    const size_t SZ = (size_t)NH * L_ * D_;
    u16* q_ws = ws;
    u16* k_ws = q_ws + SZ;
    u16* v_ws = k_ws + SZ;
    u16* o_ws = v_ws + SZ;
    u16* x_bf = o_ws + SZ;

    cvt_x<<<dim3((B_*L_*D_)/(256*8)), 256, 0, stream>>>(x, x_bf);
    qkv_proj<<<dim3(H_, (B_*L_)/128, 3), 256, 0, stream>>>(x_bf, Wq, Wk, Wv, q_ws, k_ws, v_ws);
    attn<<<dim3((L_/256)*NH), 512, 0, stream>>>(q_ws, k_ws, v_ws, o_ws);
    out_proj<<<dim3((B_*L_)/64), 256, 0, stream>>>(o_ws, Wu, bu, out);
}

// Round 11
// 124.607 us; speedup vs baseline: 1.5199x; 1.3619x over previous
//
#include <hip/hip_runtime.h>
#include <stdint.h>

#define D_ 128
#define H_ 8
#define B_ 4
#define L_ 2048
#define NH (B_*H_)

typedef __bf16 bf16x8 __attribute__((ext_vector_type(8)));
typedef float f32x4 __attribute__((ext_vector_type(4)));
typedef float f32x16 __attribute__((ext_vector_type(16)));
typedef unsigned short u16;
typedef u16 u16x2 __attribute__((ext_vector_type(2)));
typedef u16 u16x4 __attribute__((ext_vector_type(4)));
typedef u16 u16x8 __attribute__((ext_vector_type(8)));
typedef uint32_t u32x2 __attribute__((ext_vector_type(2)));
typedef uint32_t u32x4 __attribute__((ext_vector_type(4)));
typedef float fvec4 __attribute__((ext_vector_type(4)));

__device__ __forceinline__ u16 f2b(float f){
    uint32_t u = __builtin_bit_cast(uint32_t, f);
    u += 0x7fffu + ((u >> 16) & 1u);
    return (u16)(u >> 16);
}
__device__ __forceinline__ u16 f2b_native(float f){
    return __builtin_bit_cast(u16, (__bf16)f);
}
__device__ __forceinline__ uint32_t pk2(float a, float b){
    u16x2 v = { f2b_native(a), f2b_native(b) };
    return __builtin_bit_cast(uint32_t, v);
}
__device__ __forceinline__ float ex2(float x){
#if __has_builtin(__builtin_amdgcn_exp2f)
    return __builtin_amdgcn_exp2f(x);
#else
    return exp2f(x);
#endif
}
__device__ __forceinline__ u32x2 permswap(uint32_t a, uint32_t b){
#if __has_builtin(__builtin_amdgcn_permlane32_swap)
    return __builtin_amdgcn_permlane32_swap(a, b, false, false);
#else
    asm volatile("v_permlane32_swap_b32 %0, %1" : "+v"(a), "+v"(b));
    u32x2 r; r[0] = a; r[1] = b; return r;
#endif
}
__device__ __forceinline__ bf16x8 asbf(u16x8 v){ return __builtin_bit_cast(bf16x8, v); }
#define MFMA(a,b,c)   __builtin_amdgcn_mfma_f32_16x16x32_bf16((a),(b),(c),0,0,0)
#define MFMA32(a,b,c) __builtin_amdgcn_mfma_f32_32x32x16_bf16((a),(b),(c),0,0,0)

__device__ __forceinline__ void gld16(const u16* g, u16* l){
    __builtin_amdgcn_global_load_lds(
        (const __attribute__((address_space(1))) void*)g,
        (__attribute__((address_space(3))) void*)l, 16, 0, 0);
}

// ---------------- kernel 0a: convert x fp32 -> bf16 ----------------
__global__ __launch_bounds__(256)
void cvt_x(const float* __restrict__ x, u16* __restrict__ xb){
    size_t i = ((size_t)blockIdx.x*256 + threadIdx.x)*8;
    fvec4 lo = *(const fvec4*)&x[i];
    fvec4 hi = *(const fvec4*)&x[i+4];
    u16x8 u;
    for (int j=0;j<4;++j){ u[j]=f2b(lo[j]); u[4+j]=f2b(hi[j]); }
    *(u16x8*)&xb[i] = u;
}

// ---------------- kernel 0b: convert+transpose W to bf16 tiles ----------------
// Blocks 0..23: Wq/Wk/Wv (mat=b>>3, head=b&7): tile = W^T[n=within-head d][k],
// stored PRE-SWIZZLED: global granule slot g of row n holds granule (g^(n&7)).
// Blocks 24..31: Wu tile ks=b-24: WuT[n][k within ks*128..], same swizzle.
__global__ __launch_bounds__(256)
void cvt_w(const float* __restrict__ Wq, const float* __restrict__ Wk,
           const float* __restrict__ Wv, const float* __restrict__ Wu,
           u16* __restrict__ wT, u16* __restrict__ wuT)
{
    const int b = blockIdx.x;
    __shared__ __align__(16) u16 T[128][144];   // row stride 288B (16B-aligned)
    const int t = threadIdx.x;
    const float* src; int ld, coff, roff; u16* dst;
    if (b < 24){
        int mat = b>>3, head = b&7;
        src = (mat==0)?Wq:((mat==1)?Wk:Wv); ld = D_*H_; coff = head*128; roff = 0;
        dst = wT + (size_t)b*16384;
    } else {
        src = Wu; ld = D_; coff = 0; roff = (b-24)*128;
        dst = wuT + (size_t)(b-24)*16384;
    }
    for (int it=0; it<16; ++it){
        int k = it*8 + (t>>5), n0 = (t&31)*4;
        fvec4 wv = *(const fvec4*)&src[(size_t)(roff+k)*ld + coff + n0];
        for (int i=0;i<4;++i) T[n0+i][k] = f2b(wv[i]);
    }
    __syncthreads();
    for (int it=0; it<8; ++it){
        int gi = it*256 + t; int n = gi>>4, g = gi&15;
        *(u16x8*)&dst[n*128 + g*8] = *(const u16x8*)&T[n][(g^(n&7))*8];
    }
}

// ---------------- kernel 1: QKV projection (DMA-staged both operands) ----------------
// grid (8 head, 64 rt, 3 mat). 256 thr, 4 waves; 128x128 out, K=128 single step.
// Xs staged with source-side XOR swizzle; Ws staged linear (pre-swizzled by cvt_w).
// Q: q_ws[bh][l][d] (pre-scaled by log2e/sqrt(D)), K: k_ws[bh][l][d], V: v_ws[bh][d][l]
__global__ __launch_bounds__(256)
void qkv_proj(const u16* __restrict__ xb, const u16* __restrict__ wT,
              u16* __restrict__ q_ws, u16* __restrict__ k_ws, u16* __restrict__ v_ws)
{
    const int head = blockIdx.x;
    const int rt   = blockIdx.y;
    const int mat  = blockIdx.z;

    __shared__ __align__(16) u16 Xs[128*128];
    __shared__ __align__(16) u16 Ws[128*128];

    const int t = threadIdx.x;
    const int row0 = rt*128;
    const u16* wsrc = wT + (size_t)(mat*8 + head)*16384;

    // stage: 2048 granules each
    for (int it=0; it<8; ++it){
        int gi = it*256 + t;
        int r = gi>>4, g = gi&15;
        gld16(&xb[(size_t)(row0+r)*D_ + ((g ^ (r&7))*8)], &Xs[(it*256 + (t>>6)*64)*8]);
        gld16(&wsrc[gi*8],                                &Ws[(it*256 + (t>>6)*64)*8]);
    }
    asm volatile("s_waitcnt vmcnt(0)" ::: "memory");
    __builtin_amdgcn_s_barrier();

    const int wave = t>>6, lane = t&63;
    const int wr = wave>>1, wc = wave&1;
    const int lrow = lane&15, lgrp = lane>>4;
    const int swz = lrow&7;

    f32x4 acc[4][4] = {};
    #pragma unroll
    for (int kc=0;kc<4;++kc){
        const int gd = kc*4 + lgrp;
        bf16x8 a[4], bfr[4];
        #pragma unroll
        for (int mr=0;mr<4;++mr)
            a[mr] = asbf(*(const u16x8*)&Xs[(wr*64+mr*16+lrow)*128 + ((gd ^ swz)*8)]);
        #pragma unroll
        for (int nr=0;nr<4;++nr)
            bfr[nr] = asbf(*(const u16x8*)&Ws[(wc*64+nr*16+lrow)*128 + ((gd ^ swz)*8)]);
        #pragma unroll
        for (int mr=0;mr<4;++mr)
            #pragma unroll
            for (int nr=0;nr<4;++nr)
                acc[mr][nr] = MFMA(a[mr], bfr[nr], acc[mr][nr]);
    }

    const float qscale = 0.12751879455370425f;  // log2(e)/sqrt(128)
    for (int mr=0;mr<4;++mr){
        for (int nr=0;nr<4;++nr){
            f32x4 v = acc[mr][nr];
            int baserow = row0 + wr*64 + mr*16 + lgrp*4;
            int cd = wc*64 + nr*16 + lrow;
            int b  = baserow / L_;
            int l  = baserow % L_;
            int bh = b*H_ + head;
            if (mat==2){
                u16x4 pv;
                for (int r=0;r<4;++r) pv[r] = f2b(v[r]);
                *(u16x4*)&v_ws[((size_t)bh*D_ + cd)*L_ + l] = pv;
            } else {
                u16* dst = (mat==0) ? q_ws : k_ws;
                for (int r=0;r<4;++r){
                    float f = v[r];
                    if (mat==0) f *= qscale;
                    dst[((size_t)bh*L_ + (l + r))*D_ + cd] = f2b(f);
                }
            }
        }
    }
}

// ---------------- kernel 2: flash attention (unchanged from R10) ----------------
__global__ __launch_bounds__(512)
void attn(const u16* __restrict__ q_ws, const u16* __restrict__ k_ws,
          const u16* __restrict__ v_ws, u16* __restrict__ o_ws)
{
    const int wg = ((blockIdx.x & 7) << 5) | (blockIdx.x >> 3);
    const int qt = wg & 7;
    const int bh = wg >> 3;

    const int t = threadIdx.x, wave = t>>6, lane = t&63;
    const int q31 = lane & 31;
    const int hi  = lane >> 5;
    const int swq = q31 & 7;

    __shared__ __align__(16) u16 Kb[3][64*128];
    __shared__ __align__(16) u16 Vb[3][128*64];

    const int q0 = qt*256 + wave*32;

    bf16x8 qf[8];
    #pragma unroll
    for (int ks=0; ks<8; ++ks)
        qf[ks] = asbf(*(const u16x8*)&q_ws[((size_t)bh*L_ + q0 + q31)*D_ + ks*16 + hi*8]);

    const u16* kp = k_ws + (size_t)bh*L_*D_;
    const u16* vp = v_ws + (size_t)bh*D_*L_;
    int koff[2], voff[2];
    #pragma unroll
    for (int i=0;i<2;++i){
        int f = i*512 + t;
        int kr = f>>4, kc = f&15;
        koff[i] = kr*128 + ((kc ^ (kr&7))*8);
        int vr = f>>3, vc = f&7;
        voff[i] = vr*L_ + ((vc ^ (vr&7))*8);
    }

    auto stage = [&](int buf){
        #pragma unroll
        for (int i=0;i<2;++i){
            gld16(kp + koff[i], &Kb[buf][(i*512 + wave*64)*8]);
            gld16(vp + voff[i], &Vb[buf][(i*512 + wave*64)*8]);
        }
        kp += 64*D_;
        vp += 64;
    };

    float lsA = 0.f, lsB = 0.f;
    f32x16 o4[4] = {};

    stage(0);
    stage(1);
    asm volatile("s_waitcnt vmcnt(4)" ::: "memory");
    __builtin_amdgcn_s_barrier();

    for (int kt=0; kt<L_/64; ++kt){
        const int cur = kt % 3;
        if (kt < L_/64 - 2) stage((kt+2) % 3);

        f32x16 s0a = {}, s0b = {}, s1a = {}, s1b = {};
        __builtin_amdgcn_s_setprio(1);
        #pragma unroll
        for (int ks=0; ks<4; ++ks){
            bf16x8 ka0 = asbf(*(const u16x8*)&Kb[cur][q31*128      + (((ks*2+hi)     ^ swq)*8)]);
            bf16x8 ka1 = asbf(*(const u16x8*)&Kb[cur][q31*128      + ((((ks+4)*2+hi) ^ swq)*8)]);
            bf16x8 kb0 = asbf(*(const u16x8*)&Kb[cur][(32+q31)*128 + (((ks*2+hi)     ^ swq)*8)]);
            bf16x8 kb1 = asbf(*(const u16x8*)&Kb[cur][(32+q31)*128 + ((((ks+4)*2+hi) ^ swq)*8)]);
            s0a = MFMA32(ka0, qf[ks],   s0a);
            s0b = MFMA32(ka1, qf[ks+4], s0b);
            s1a = MFMA32(kb0, qf[ks],   s1a);
            s1b = MFMA32(kb1, qf[ks+4], s1b);
        }
        __builtin_amdgcn_s_setprio(0);
        f32x16 s0 = s0a + s0b;
        f32x16 s1 = s1a + s1b;

        #define SM_PV(SREG, KS) do { \
            float p0 = ex2(SREG[((KS&1)*8)+0]); \
            float p1 = ex2(SREG[((KS&1)*8)+1]); \
            float p2 = ex2(SREG[((KS&1)*8)+2]); \
            float p3 = ex2(SREG[((KS&1)*8)+3]); \
            float p4 = ex2(SREG[((KS&1)*8)+4]); \
            float p5 = ex2(SREG[((KS&1)*8)+5]); \
            float p6 = ex2(SREG[((KS&1)*8)+6]); \
            float p7 = ex2(SREG[((KS&1)*8)+7]); \
            lsA += (p0+p1)+(p2+p3); \
            lsB += (p4+p5)+(p6+p7); \
            uint32_t cA = pk2(p0,p1), cB = pk2(p2,p3); \
            uint32_t cC = pk2(p4,p5), cD = pk2(p6,p7); \
            u32x2 r0 = permswap(cA, cC); \
            u32x2 r1 = permswap(cB, cD); \
            u32x4 wv; \
            wv[0] = r0[0];  wv[1] = r1[0]; \
            wv[2] = r0[1];  wv[3] = r1[1]; \
            bf16x8 pa = __builtin_bit_cast(bf16x8, wv); \
            __builtin_amdgcn_s_setprio(1); \
            _Pragma("unroll") \
            for (int nc2=0; nc2<4; ++nc2){ \
                bf16x8 vb = asbf(*(const u16x8*)&Vb[cur][ (nc2*32+q31)*64 + (((KS*2+hi) ^ swq)*8) ]); \
                o4[nc2] = MFMA32(pa, vb, o4[nc2]); \
            } \
            __builtin_amdgcn_s_setprio(0); \
        } while(0)

        SM_PV(s0, 0);
        SM_PV(s0, 1);
        SM_PV(s1, 2);
        SM_PV(s1, 3);
        #undef SM_PV

        if (kt < L_/64 - 1){
            if (kt < L_/64 - 2) asm volatile("s_waitcnt vmcnt(4)" ::: "memory");
            else                asm volatile("s_waitcnt vmcnt(0)" ::: "memory");
            __builtin_amdgcn_s_barrier();
        }
    }

    float lsum = lsA + lsB;
    lsum += __shfl_xor(lsum, 32, 64);
    float inv = 1.0f / lsum;

    const int b = bh / H_, h = bh % H_;
    #pragma unroll
    for (int m=0; m<4; ++m){
        #pragma unroll
        for (int i=0; i<4; ++i){
            const int reg = m*4 + i;
            const int row = i + 8*m + 4*hi;
            float riv = __shfl(inv, row, 64);
            const int l = q0 + row;
            size_t base = ((size_t)(b*L_ + l))*(D_*H_) + h*128 + q31;
            #pragma unroll
            for (int nc2=0; nc2<4; ++nc2)
                o_ws[base + nc2*32] = f2b_native(o4[nc2][reg] * riv);
        }
    }
}

// ---------------- kernel 3: output projection + bias (DMA-staged) ----------------
// 256 blocks x 32 rows. 4 waves: (wr=rows 2x16, wc=cols 2x64). K=1024 in 8 ks steps.
// As staged with source swizzle; Ws staged linear (pre-swizzled WuT tiles).
__global__ __launch_bounds__(256)
void out_proj(const u16* __restrict__ o_ws, const u16* __restrict__ wuT,
              const float* __restrict__ bu, float* __restrict__ out)
{
    const int rt = blockIdx.x;
    const int t = threadIdx.x, wave = t>>6, lane = t&63;
    const int wr = wave>>1, wc = wave&1;
    const int lrow = lane&15, lgrp = lane>>4;
    const int swz = lrow&7;

    __shared__ __align__(16) u16 As[32*128];
    __shared__ __align__(16) u16 Ws[128*128];

    const int row0 = rt*32;
    f32x4 acc[4] = {};

    for (int ks=0; ks<8; ++ks){
        if (ks) __builtin_amdgcn_s_barrier();   // prev compute done before overwrite
        // As: 512 granules (2/thread); Ws: 2048 granules (8/thread)
        {
            int gi = t;           // 0..255
            int r = gi>>4, g = gi&15;
            gld16(&o_ws[(size_t)(row0+r)*(D_*H_) + ks*128 + ((g ^ (r&7))*8)], &As[((t>>6)*64)*8]);
            gi = 256 + t;
            r = gi>>4; g = gi&15;
            gld16(&o_ws[(size_t)(row0+r)*(D_*H_) + ks*128 + ((g ^ (r&7))*8)], &As[(256 + (t>>6)*64)*8]);
        }
        const u16* wsrc = wuT + (size_t)ks*16384;
        for (int it=0; it<8; ++it)
            gld16(&wsrc[(it*256 + t)*8], &Ws[(it*256 + (t>>6)*64)*8]);
        asm volatile("s_waitcnt vmcnt(0)" ::: "memory");
        __builtin_amdgcn_s_barrier();

        #pragma unroll
        for (int kc=0;kc<4;++kc){
            const int gd = kc*4 + lgrp;
            bf16x8 a = asbf(*(const u16x8*)&As[(wr*16+lrow)*128 + ((gd ^ swz)*8)]);
            #pragma unroll
            for (int nc=0;nc<4;++nc){
                bf16x8 b = asbf(*(const u16x8*)&Ws[(wc*64+nc*16+lrow)*128 + ((gd ^ swz)*8)]);
                acc[nc] = MFMA(a, b, acc[nc]);
            }
        }
    }

    for (int nc=0;nc<4;++nc){
        for (int r=0;r<4;++r){
            int row = row0 + wr*16 + lgrp*4 + r;
            int n = wc*64 + nc*16 + lrow;
            out[(size_t)row*D_ + n] = acc[nc][r] + bu[n];
        }
    }
}

// ---------------- launcher ----------------
extern "C" void kernel_launch(void* const* d_in, const int* in_sizes, int n_in,
                              void* d_out, int out_size, void* d_ws, size_t ws_size,
                              hipStream_t stream)
{
    const float* x  = (const float*)d_in[0];
    const float* Wq = (const float*)d_in[1];
    const float* Wk = (const float*)d_in[2];
    const float* Wv = (const float*)d_in[3];
    const float* Wu = (const float*)d_in[4];
    const float* bu = (const float*)d_in[5];
    float* out = (float*)d_out;

    u16* ws = (u16*)d_ws;
    const size_t SZ = (size_t)NH * L_ * D_;   // 8,388,608
    u16* q_ws = ws;
    u16* k_ws = q_ws + SZ;
    u16* v_ws = k_ws + SZ;
    u16* o_ws = v_ws + SZ;
    u16* x_bf = o_ws + SZ;                    // 1,048,576
    u16* wT   = x_bf + (size_t)B_*L_*D_;      // 24*16384 = 393,216
    u16* wuT  = wT + 24*16384;                // 8*16384  = 131,072

    cvt_x<<<dim3((B_*L_*D_)/(256*8)), 256, 0, stream>>>(x, x_bf);
    cvt_w<<<dim3(32), 256, 0, stream>>>(Wq, Wk, Wv, Wu, wT, wuT);
    qkv_proj<<<dim3(H_, (B_*L_)/128, 3), 256, 0, stream>>>(x_bf, wT, q_ws, k_ws, v_ws);
    attn<<<dim3((L_/256)*NH), 512, 0, stream>>>(q_ws, k_ws, v_ws, o_ws);
    out_proj<<<dim3((B_*L_)/32), 256, 0, stream>>>(o_ws, wuT, bu, out);
}